// Round 3
// baseline (247.934 us; speedup 1.0000x reference)
//
#include <hip/hip_runtime.h>
#include <math.h>

// Problem constants (match reference)
constexpr int B_ = 512;
constexpr int N_ = 128;
constexpr int D_ = 512;
constexpr float TEMP_INV = 1.0f / 0.07f;
constexpr float NEG_INF_ = -1e9f;
constexpr float EPS_ = 1e-12f;

typedef float f4v __attribute__((ext_vector_type(4)));

// Workspace layout (in floats)
constexpr size_t OFF_TN   = 0;                          // B*D normalized text
constexpr size_t OFF_GTV  = OFF_TN + (size_t)B_ * D_;   // B*D normalized gt visuals
constexpr size_t OFF_POS  = OFF_GTV + (size_t)B_ * D_;  // B   pos_sim
constexpr size_t OFF_LIN  = OFF_POS + B_;               // B*N in-sample logits
constexpr size_t OFF_SV   = OFF_LIN + (size_t)B_ * N_;  // B   sample_valid (int)
constexpr size_t OFF_SCAL = OFF_SV + B_;                // accum[2], done (3 words)

__device__ __forceinline__ float wave_sum(float v) {
    for (int off = 32; off; off >>= 1) v += __shfl_xor(v, off);
    return v;
}

// Wave-local dtype detection for `valid`: scan first 64 words (L1-broadcast).
__device__ __forceinline__ void detect_flags(const void* raw, int lane, int& f0, int& f1) {
    unsigned int v = ((const unsigned int*)raw)[lane];
    f0 = (__ballot(v == 0x3f800000u) != 0ull) ? 1 : 0;
    f1 = (__ballot((v & 0xffffff00u) != 0u) != 0ull) ? 1 : 0;
}

__device__ __forceinline__ int decode_valid(const void* raw, int f0, int f1, size_t idx) {
    if (f0) return ((const float*)raw)[idx] != 0.0f;
    if (f1) return ((const unsigned char*)raw)[idx] != 0;
    return ((const int*)raw)[idx] != 0;
}

// ---------------------------------------------------------------------------
// Fused: dtype-detect + text-normalize + in-sample logits + GT-row
// (gtv/pos_sim/svalid) + scalar zero-init. Grid = B*4; block = one b, one
// 32-row tile. Quarter-wave dots; visual streamed with NONTEMPORAL loads
// (read-once, keeps tn/gtv/lin L2-hot for the second kernel).
__global__ __launch_bounds__(256) void fused_insample_kernel(
        const float* __restrict__ text,
        const float* __restrict__ visual,
        const int* __restrict__ gt,
        const void* __restrict__ valid_raw,
        float* __restrict__ tn,
        float* __restrict__ gtv,
        float* __restrict__ pos_sim,
        int* __restrict__ svalid,
        float* __restrict__ scal,   // accum[2], done — zeroed here
        float* __restrict__ lin) {
    int bid = blockIdx.x;
    int b = bid >> 2;
    int tile = bid & 3;
    int tid = threadIdx.x;
    int wave = tid >> 6, lane = tid & 63;

    if (bid == 0 && tid < 3) scal[tid] = 0.0f;   // accum[0..1], done

    int f0, f1;
    detect_flags(valid_raw, lane, f0, f1);       // wave-uniform, no sync needed

    // stage + normalize text row in LDS (4x redundant across tiles; L2-hot)
    __shared__ float4 tsh4[D_ / 4];
    float* tshf = (float*)tsh4;
    const float* trow = text + (size_t)b * D_;
    float t0 = trow[tid], t1 = trow[tid + 256];
    float sst = wave_sum(t0 * t0 + t1 * t1);
    __shared__ float red[4];
    __shared__ float invt_sh;
    if (lane == 0) red[wave] = sst;
    __syncthreads();
    if (tid == 0) invt_sh = 1.0f / fmaxf(sqrtf(red[0] + red[1] + red[2] + red[3]), EPS_);
    __syncthreads();
    float invt = invt_sh;
    t0 *= invt; t1 *= invt;
    tshf[tid] = t0; tshf[tid + 256] = t1;
    if (tile == 0) {                              // one tile publishes tn
        tn[(size_t)b * D_ + tid]       = t0;
        tn[(size_t)b * D_ + tid + 256] = t1;
    }
    __syncthreads();

    int g = gt[b];
    int gc = min(max(g, 0), N_ - 1);
    int sub = lane >> 4;      // row within wave (0..3)
    int s = lane & 15;        // lane within quarter-wave

    #pragma unroll
    for (int p = 0; p < 2; ++p) {
        int n = tile * 32 + p * 16 + wave * 4 + sub;
        const f4v* vrow = (const f4v*)(visual + ((size_t)b * N_ + n) * D_);
        float dot = 0.0f, ss = 0.0f;
        #pragma unroll
        for (int it = 0; it < 8; ++it) {
            f4v v = __builtin_nontemporal_load(vrow + s + 16 * it);
            float4 t = tsh4[s + 16 * it];
            dot += v.x * t.x + v.y * t.y + v.z * t.z + v.w * t.w;
            ss  += v.x * v.x + v.y * v.y + v.z * v.z + v.w * v.w;
        }
        #pragma unroll
        for (int off = 8; off; off >>= 1) {       // butterfly: all 16 lanes get result
            dot += __shfl_xor(dot, off);
            ss  += __shfl_xor(ss, off);
        }
        float inv = 1.0f / fmaxf(sqrtf(ss), EPS_);
        if (s == 0) {
            int vb = decode_valid(valid_raw, f0, f1, (size_t)b * N_ + n);
            bool m = vb && (n != gc);
            lin[(size_t)b * N_ + n] = m ? dot * inv * TEMP_INV : NEG_INF_;
            if (n == gc) {
                pos_sim[b] = dot * inv * TEMP_INV;
                svalid[b] = (g >= 0 && g < N_ && vb) ? 1 : 0;
            }
        }
        if (n == gc) {   // quarter-wave writes normalized GT row from registers
            f4v* gdst = (f4v*)(gtv + (size_t)b * D_);
            #pragma unroll
            for (int it = 0; it < 8; ++it) {
                f4v v = __builtin_nontemporal_load(vrow + s + 16 * it);
                gdst[s + 16 * it] = v * inv;
            }
        }
    }
}

// ---------------------------------------------------------------------------
// Fused batch-logits + LSE + output. Grid = B_/4 = 128 blocks x 512 threads;
// each block owns 4 b-rows (halves gtv L2 traffic vs 2-row version: 128 MB
// total). Batch logits live in LDS; LSE runs 4 rows x 128 threads (2 aligned
// waves per row). Last block writes the two outputs.
__global__ __launch_bounds__(512) void batch_lse_kernel(
        const float* __restrict__ gtv,
        const float* __restrict__ tn,
        const float* __restrict__ lin,
        const float* __restrict__ pos_sim,
        const int* __restrict__ svalid,
        float* __restrict__ accum,
        int* __restrict__ done,
        float* __restrict__ out) {
    int b0 = blockIdx.x * 4;
    int tid = threadIdx.x;
    int wave = tid >> 6, lane = tid & 63;

    __shared__ float4 tsh[4 * (D_ / 4)];   // 4 tn rows, 8 KB
    __shared__ float lbsh[4][B_];          // 4 rows of batch logits, 8 KB
    {
        int idx = tid;                      // 512 threads == 512 float4 slots
        int r = idx >> 7, c = idx & 127;
        tsh[idx] = ((const float4*)tn)[(size_t)(b0 + r) * (D_ / 4) + c];
    }
    __syncthreads();

    // 32 quarter-waves (q = tid>>4); each does 16 j-rows against 4 t-rows.
    int q = tid >> 4;
    int s = tid & 15;
    #pragma unroll 4
    for (int p = 0; p < 16; ++p) {
        int j = p * 32 + q;
        const float4* grow = (const float4*)gtv + (size_t)j * (D_ / 4);
        float a0 = 0.0f, a1 = 0.0f, a2 = 0.0f, a3 = 0.0f;
        #pragma unroll
        for (int it = 0; it < 8; ++it) {
            float4 v  = grow[s + 16 * it];
            float4 t0 = tsh[0 * 128 + s + 16 * it];
            float4 t1 = tsh[1 * 128 + s + 16 * it];
            float4 t2 = tsh[2 * 128 + s + 16 * it];
            float4 t3 = tsh[3 * 128 + s + 16 * it];
            a0 += v.x * t0.x + v.y * t0.y + v.z * t0.z + v.w * t0.w;
            a1 += v.x * t1.x + v.y * t1.y + v.z * t1.z + v.w * t1.w;
            a2 += v.x * t2.x + v.y * t2.y + v.z * t2.z + v.w * t2.w;
            a3 += v.x * t3.x + v.y * t3.y + v.z * t3.z + v.w * t3.w;
        }
        #pragma unroll
        for (int off = 8; off; off >>= 1) {
            a0 += __shfl_xor(a0, off);
            a1 += __shfl_xor(a1, off);
            a2 += __shfl_xor(a2, off);
            a3 += __shfl_xor(a3, off);
        }
        int sv = svalid[j];
        if (s < 4) {
            float av = (s == 0) ? a0 : (s == 1) ? a1 : (s == 2) ? a2 : a3;
            int brow = b0 + s;
            lbsh[s][j] = (sv && j != brow) ? av * TEMP_INV : NEG_INF_;
        }
    }
    __syncthreads();

    // LSE over [pos, 128 lin, 512 lbsh]: row r = tid>>7 (2 aligned waves/row),
    // rt = tid&127. Each thread: 1 lin value + 4 lbsh values.
    int r = tid >> 7;        // 0..3
    int rt = tid & 127;      // thread within row
    int b = b0 + r;
    float pos = pos_sim[b];
    float xa = lin[(size_t)b * N_ + rt];
    float xb = lbsh[r][rt];
    float xc = lbsh[r][rt + 128];
    float xd = lbsh[r][rt + 256];
    float xe = lbsh[r][rt + 384];
    float lmax = fmaxf(fmaxf(fmaxf(xa, xb), fmaxf(xc, xd)), xe);
    for (int off = 32; off; off >>= 1) lmax = fmaxf(lmax, __shfl_xor(lmax, off));
    __shared__ float redm[8], reds[8];
    if (lane == 0) redm[wave] = lmax;
    __syncthreads();
    float maxneg = fmaxf(redm[r * 2], redm[r * 2 + 1]);
    float m = fmaxf(maxneg, pos);
    float lsum = __expf(xa - m) + __expf(xb - m) + __expf(xc - m)
               + __expf(xd - m) + __expf(xe - m);
    lsum = wave_sum(lsum);
    if (lane == 0) reds[wave] = lsum;
    __syncthreads();
    __shared__ int is_last;
    if (rt == 0) {   // tids 0,128,256,384 — one leader per row
        float sum = reds[r * 2] + reds[r * 2 + 1] + __expf(pos - m);
        float lse = m + logf(sum);
        float loss = lse - pos;
        bool has_neg = maxneg > -1e8f;
        bool contrib = (svalid[b] != 0) && has_neg;
        if (contrib) {
            atomicAdd(&accum[0], loss);
            if (pos >= maxneg) atomicAdd(&accum[1], 1.0f);
        }
        __threadfence();   // row-leaders flush their atomics before done++
    }
    __syncthreads();       // barrier drains outstanding memory ops
    if (tid == 0) {
        int prev = atomicAdd(done, 1);
        is_last = (prev == (int)gridDim.x - 1) ? 1 : 0;
    }
    __syncthreads();
    if (is_last) {
        int v = svalid[tid];   // 512 threads cover all of svalid
        for (int off = 32; off; off >>= 1) v += __shfl_xor(v, off);
        __shared__ int ired[8];
        if (lane == 0) ired[wave] = v;
        __syncthreads();
        if (tid == 0) {
            int nv = 0;
            #pragma unroll
            for (int w = 0; w < 8; ++w) nv += ired[w];
            float total = atomicAdd(&accum[0], 0.0f);  // coherent read via RMW
            float acc   = atomicAdd(&accum[1], 0.0f);
            float denom = fmaxf((float)nv, 1.0f);
            out[0] = total / denom;
            out[1] = acc / denom;
        }
    }
}

// ---------------------------------------------------------------------------
extern "C" void kernel_launch(void* const* d_in, const int* in_sizes, int n_in,
                              void* d_out, int out_size, void* d_ws, size_t ws_size,
                              hipStream_t stream) {
    const float* text   = (const float*)d_in[0];
    const float* visual = (const float*)d_in[1];
    const void*  valid  = d_in[2];
    const int*   gt     = (const int*)d_in[3];
    float* out = (float*)d_out;

    float* wsf = (float*)d_ws;
    float* tn      = wsf + OFF_TN;
    float* gtv     = wsf + OFF_GTV;
    float* pos_sim = wsf + OFF_POS;
    float* lin     = wsf + OFF_LIN;
    int*   svalid  = (int*)(wsf + OFF_SV);
    float* scal    = wsf + OFF_SCAL;               // accum[0..1], done
    float* accum   = scal;
    int*   done    = (int*)(scal + 2);

    fused_insample_kernel<<<B_ * 4, 256, 0, stream>>>(text, visual, gt, valid,
                                                      tn, gtv, pos_sim, svalid, scal, lin);
    batch_lse_kernel<<<B_ / 4, 512, 0, stream>>>(gtv, tn, lin, pos_sim, svalid,
                                                 accum, done, out);
}

// Round 4
// 213.384 us; speedup vs baseline: 1.1619x; 1.1619x over previous
//
#include <hip/hip_runtime.h>
#include <math.h>

// Problem constants (match reference)
constexpr int B_ = 512;
constexpr int N_ = 128;
constexpr int D_ = 512;
constexpr float TEMP_INV = 1.0f / 0.07f;
constexpr float NEG_INF_ = -1e9f;
constexpr float EPS_ = 1e-12f;

typedef float f4v __attribute__((ext_vector_type(4)));

// Workspace layout (in floats)
constexpr size_t OFF_TN   = 0;                          // B*D normalized text
constexpr size_t OFF_GTV  = OFF_TN + (size_t)B_ * D_;   // B*D normalized gt visuals
constexpr size_t OFF_POS  = OFF_GTV + (size_t)B_ * D_;  // B   pos_sim
constexpr size_t OFF_LIN  = OFF_POS + B_;               // B*N in-sample logits
constexpr size_t OFF_SV   = OFF_LIN + (size_t)B_ * N_;  // B   sample_valid (int)
constexpr size_t OFF_SCAL = OFF_SV + B_;                // accum[2], done (3 words)

__device__ __forceinline__ float wave_sum(float v) {
    for (int off = 32; off; off >>= 1) v += __shfl_xor(v, off);
    return v;
}

// Wave-local dtype detection for `valid`: scan first 64 words (L1-broadcast).
__device__ __forceinline__ void detect_flags(const void* raw, int lane, int& f0, int& f1) {
    unsigned int v = ((const unsigned int*)raw)[lane];
    f0 = (__ballot(v == 0x3f800000u) != 0ull) ? 1 : 0;
    f1 = (__ballot((v & 0xffffff00u) != 0u) != 0ull) ? 1 : 0;
}

__device__ __forceinline__ int decode_valid(const void* raw, int f0, int f1, size_t idx) {
    if (f0) return ((const float*)raw)[idx] != 0.0f;
    if (f1) return ((const unsigned char*)raw)[idx] != 0;
    return ((const int*)raw)[idx] != 0;
}

// ---------------------------------------------------------------------------
// Fused: dtype-detect + text-normalize + in-sample logits + GT-row
// (gtv/pos_sim/svalid) + scalar zero-init. Grid = B*4; block = one b, one
// 32-row tile. Quarter-wave dots; visual streamed with NONTEMPORAL loads
// (read-once, keeps tn/gtv/lin L2-hot for the second kernel).
__global__ __launch_bounds__(256) void fused_insample_kernel(
        const float* __restrict__ text,
        const float* __restrict__ visual,
        const int* __restrict__ gt,
        const void* __restrict__ valid_raw,
        float* __restrict__ tn,
        float* __restrict__ gtv,
        float* __restrict__ pos_sim,
        int* __restrict__ svalid,
        float* __restrict__ scal,   // accum[2], done — zeroed here
        float* __restrict__ lin) {
    int bid = blockIdx.x;
    int b = bid >> 2;
    int tile = bid & 3;
    int tid = threadIdx.x;
    int wave = tid >> 6, lane = tid & 63;

    if (bid == 0 && tid < 3) scal[tid] = 0.0f;   // accum[0..1], done

    int f0, f1;
    detect_flags(valid_raw, lane, f0, f1);       // wave-uniform, no sync needed

    // stage + normalize text row in LDS (4x redundant across tiles; L2-hot)
    __shared__ float4 tsh4[D_ / 4];
    float* tshf = (float*)tsh4;
    const float* trow = text + (size_t)b * D_;
    float t0 = trow[tid], t1 = trow[tid + 256];
    float sst = wave_sum(t0 * t0 + t1 * t1);
    __shared__ float red[4];
    __shared__ float invt_sh;
    if (lane == 0) red[wave] = sst;
    __syncthreads();
    if (tid == 0) invt_sh = 1.0f / fmaxf(sqrtf(red[0] + red[1] + red[2] + red[3]), EPS_);
    __syncthreads();
    float invt = invt_sh;
    t0 *= invt; t1 *= invt;
    tshf[tid] = t0; tshf[tid + 256] = t1;
    if (tile == 0) {                              // one tile publishes tn
        tn[(size_t)b * D_ + tid]       = t0;
        tn[(size_t)b * D_ + tid + 256] = t1;
    }
    __syncthreads();

    int g = gt[b];
    int gc = min(max(g, 0), N_ - 1);
    int sub = lane >> 4;      // row within wave (0..3)
    int s = lane & 15;        // lane within quarter-wave

    #pragma unroll
    for (int p = 0; p < 2; ++p) {
        int n = tile * 32 + p * 16 + wave * 4 + sub;
        const f4v* vrow = (const f4v*)(visual + ((size_t)b * N_ + n) * D_);
        float dot = 0.0f, ss = 0.0f;
        #pragma unroll
        for (int it = 0; it < 8; ++it) {
            f4v v = __builtin_nontemporal_load(vrow + s + 16 * it);
            float4 t = tsh4[s + 16 * it];
            dot += v.x * t.x + v.y * t.y + v.z * t.z + v.w * t.w;
            ss  += v.x * v.x + v.y * v.y + v.z * v.z + v.w * v.w;
        }
        #pragma unroll
        for (int off = 8; off; off >>= 1) {       // butterfly: all 16 lanes get result
            dot += __shfl_xor(dot, off);
            ss  += __shfl_xor(ss, off);
        }
        float inv = 1.0f / fmaxf(sqrtf(ss), EPS_);
        if (s == 0) {
            int vb = decode_valid(valid_raw, f0, f1, (size_t)b * N_ + n);
            bool m = vb && (n != gc);
            lin[(size_t)b * N_ + n] = m ? dot * inv * TEMP_INV : NEG_INF_;
            if (n == gc) {
                pos_sim[b] = dot * inv * TEMP_INV;
                svalid[b] = (g >= 0 && g < N_ && vb) ? 1 : 0;
            }
        }
        if (n == gc) {   // quarter-wave writes normalized GT row from registers
            f4v* gdst = (f4v*)(gtv + (size_t)b * D_);
            #pragma unroll
            for (int it = 0; it < 8; ++it) {
                f4v v = __builtin_nontemporal_load(vrow + s + 16 * it);
                gdst[s + 16 * it] = v * inv;
            }
        }
    }
}

// ---------------------------------------------------------------------------
// Fused batch-logits + LSE + output. Grid = B_/2 = 256 blocks x 512 threads
// (1 block/CU); each block owns 2 b-rows. The two tn rows are hoisted into
// REGISTERS (loop-invariant per quarter-wave lane: 16 x f4v) so the dot loop
// has ZERO LDS reads — round-3 showed the loop is LDS-pipe-bound, not
// L2-bound. Batch logits live in LDS; LSE + accumulation in-block; last
// block writes the two outputs.
__global__ __launch_bounds__(512) void batch_lse_kernel(
        const float* __restrict__ gtv,
        const float* __restrict__ tn,
        const float* __restrict__ lin,
        const float* __restrict__ pos_sim,
        const int* __restrict__ svalid,
        float* __restrict__ accum,
        int* __restrict__ done,
        float* __restrict__ out) {
    int b0 = blockIdx.x * 2;
    int tid = threadIdx.x;
    int wave = tid >> 6, lane = tid & 63;

    __shared__ float lbsh[2][B_];          // 2 rows of batch logits, 4 KB

    int q = tid >> 4;        // quarter-wave id 0..31
    int s = tid & 15;        // lane within quarter-wave

    // Hoist both tn rows into registers: lane s owns float4s {s+16*it}.
    // L2-hot broadcast (all 32 quarter-waves read the same 2 rows).
    f4v rt0[8], rt1[8];
    const f4v* t0p = (const f4v*)(tn + (size_t)b0 * D_);
    const f4v* t1p = (const f4v*)(tn + (size_t)(b0 + 1) * D_);
    #pragma unroll
    for (int it = 0; it < 8; ++it) {
        rt0[it] = t0p[s + 16 * it];
        rt1[it] = t1p[s + 16 * it];
    }

    // 32 quarter-waves; each does 16 j-rows. Inner loop: 1 L2 load + 8 FMA.
    #pragma unroll 2
    for (int p = 0; p < 16; ++p) {
        int j = p * 32 + q;
        const f4v* grow = (const f4v*)(gtv + (size_t)j * D_);
        float a0 = 0.0f, a1 = 0.0f;
        #pragma unroll
        for (int it = 0; it < 8; ++it) {
            f4v v = grow[s + 16 * it];
            a0 += v.x * rt0[it].x + v.y * rt0[it].y + v.z * rt0[it].z + v.w * rt0[it].w;
            a1 += v.x * rt1[it].x + v.y * rt1[it].y + v.z * rt1[it].z + v.w * rt1[it].w;
        }
        #pragma unroll
        for (int off = 8; off; off >>= 1) {
            a0 += __shfl_xor(a0, off);
            a1 += __shfl_xor(a1, off);
        }
        if (s < 2) {
            float av = (s == 0) ? a0 : a1;
            int brow = b0 + s;
            lbsh[s][j] = (svalid[j] && j != brow) ? av * TEMP_INV : NEG_INF_;
        }
    }
    __syncthreads();

    // LSE over [pos, 128 lin, 512 lbsh]: waves 0-3 -> row 0, waves 4-7 -> row 1
    int r = tid >> 8;        // 0 or 1
    int rt = tid & 255;      // thread within row
    int b = b0 + r;
    float pos = pos_sim[b];
    float x0 = (rt < N_) ? lin[(size_t)b * N_ + rt] : lbsh[r][rt - N_];
    float x1 = lbsh[r][rt + 256 - N_];
    float x2 = (rt < N_) ? lbsh[r][rt + 512 - N_] : NEG_INF_;
    float lmax = fmaxf(fmaxf(x0, x1), x2);
    for (int off = 32; off; off >>= 1) lmax = fmaxf(lmax, __shfl_xor(lmax, off));
    __shared__ float redm[8], reds[8];
    if (lane == 0) redm[wave] = lmax;
    __syncthreads();
    float maxneg = fmaxf(fmaxf(redm[r * 4 + 0], redm[r * 4 + 1]),
                         fmaxf(redm[r * 4 + 2], redm[r * 4 + 3]));
    float m = fmaxf(maxneg, pos);
    float lsum = __expf(x0 - m) + __expf(x1 - m) + ((rt < N_) ? __expf(x2 - m) : 0.0f);
    lsum = wave_sum(lsum);
    if (lane == 0) reds[wave] = lsum;
    __syncthreads();
    __shared__ int is_last;
    if (rt == 0) {   // tid 0 (row 0) and tid 256 (row 1)
        float sum = reds[r * 4 + 0] + reds[r * 4 + 1] + reds[r * 4 + 2] + reds[r * 4 + 3]
                  + __expf(pos - m);
        float lse = m + logf(sum);
        float loss = lse - pos;
        bool has_neg = maxneg > -1e8f;
        bool contrib = (svalid[b] != 0) && has_neg;
        if (contrib) {
            atomicAdd(&accum[0], loss);
            if (pos >= maxneg) atomicAdd(&accum[1], 1.0f);
        }
        __threadfence();   // both row-leaders flush their atomics before done++
    }
    __syncthreads();       // barrier drains outstanding memory ops
    if (tid == 0) {
        int prev = atomicAdd(done, 1);
        is_last = (prev == (int)gridDim.x - 1) ? 1 : 0;
    }
    __syncthreads();
    if (is_last) {
        int v = svalid[tid];   // 512 threads cover all of svalid
        for (int off = 32; off; off >>= 1) v += __shfl_xor(v, off);
        __shared__ int ired[8];
        if (lane == 0) ired[wave] = v;
        __syncthreads();
        if (tid == 0) {
            int nv = 0;
            #pragma unroll
            for (int w = 0; w < 8; ++w) nv += ired[w];
            float total = atomicAdd(&accum[0], 0.0f);  // coherent read via RMW
            float acc   = atomicAdd(&accum[1], 0.0f);
            float denom = fmaxf((float)nv, 1.0f);
            out[0] = total / denom;
            out[1] = acc / denom;
        }
    }
}

// ---------------------------------------------------------------------------
extern "C" void kernel_launch(void* const* d_in, const int* in_sizes, int n_in,
                              void* d_out, int out_size, void* d_ws, size_t ws_size,
                              hipStream_t stream) {
    const float* text   = (const float*)d_in[0];
    const float* visual = (const float*)d_in[1];
    const void*  valid  = d_in[2];
    const int*   gt     = (const int*)d_in[3];
    float* out = (float*)d_out;

    float* wsf = (float*)d_ws;
    float* tn      = wsf + OFF_TN;
    float* gtv     = wsf + OFF_GTV;
    float* pos_sim = wsf + OFF_POS;
    float* lin     = wsf + OFF_LIN;
    int*   svalid  = (int*)(wsf + OFF_SV);
    float* scal    = wsf + OFF_SCAL;               // accum[0..1], done
    float* accum   = scal;
    int*   done    = (int*)(scal + 2);

    fused_insample_kernel<<<B_ * 4, 256, 0, stream>>>(text, visual, gt, valid,
                                                      tn, gtv, pos_sim, svalid, scal, lin);
    batch_lse_kernel<<<B_ / 2, 512, 0, stream>>>(gtv, tn, lin, pos_sim, svalid,
                                                 accum, done, out);
}